// Round 9
// baseline (140.140 us; speedup 1.0000x reference)
//
#include <hip/hip_runtime.h>
#include <hip/hip_bf16.h>
#include <stdint.h>

#define KNN 8
#define S_ 5
#define D_ 5
#define NDE 4
#define NDC 12
#define NDCP 13
#define NDD 16
#define NPOS 80
#define ACT 5
#define PERK 172
#define XROW 1376
#define FEAT 784
#define FEATP 800
#define KSTEPS 25
#define H1 512

typedef __bf16 bf16x8 __attribute__((ext_vector_type(8)));
typedef float f32x4 __attribute__((ext_vector_type(4)));

static __device__ __forceinline__ unsigned short f2bf(float f) {
    unsigned int u = __builtin_bit_cast(unsigned int, f);
    u += 0x7fff + ((u >> 16) & 1);   // round-to-nearest-even
    return (unsigned short)(u >> 16);
}
static __device__ __forceinline__ float fsgnsqrt(float t) {
    return copysignf(sqrtf(fabsf(t)), t);
}

// ---------------- K1 (fused): feat blocks [0,nB) | W1->bf16 blocks [nB,nB+800) | noisy block ----------------
__global__ __launch_bounds__(128) void k_pre(const float* __restrict__ x,
                                             const float* __restrict__ Wg,
                                             const float* __restrict__ bg,
                                             unsigned short* __restrict__ featbf,
                                             const float* __restrict__ W1,
                                             unsigned short* __restrict__ w1bf,
                                             const float* __restrict__ adv_uw,
                                             const float* __restrict__ adv_sw,
                                             const float* __restrict__ adv_ub,
                                             const float* __restrict__ adv_sb,
                                             const float* __restrict__ v_uw,
                                             const float* __restrict__ v_sw,
                                             const float* __restrict__ v_ub,
                                             const float* __restrict__ v_sb,
                                             const float* __restrict__ ei_a,
                                             const float* __restrict__ eo_a,
                                             const float* __restrict__ ei_v,
                                             const float* __restrict__ eo_v,
                                             float* __restrict__ wv,
                                             float* __restrict__ bias,
                                             int nB)
{
    const int bid = blockIdx.x;
    const int tid = threadIdx.x;

    if (bid >= nB) {
        int pb = bid - nB;
        if (pb < 800) {
            // W1 f32 -> bf16, K-pad 784->800; 4 elements per thread
            int idx0 = (pb * 128 + tid) * 4;
            int n = idx0 / FEATP, k = idx0 - n * FEATP;
            ushort4 o;
            if (k < FEAT) {   // groups never straddle the 784 boundary (784%4==0)
                float4 v = *(const float4*)(W1 + (size_t)n * FEAT + k);
                o.x = f2bf(v.x); o.y = f2bf(v.y); o.z = f2bf(v.z); o.w = f2bf(v.w);
            } else {
                o.x = o.y = o.z = o.w = 0;
            }
            *(ushort4*)(w1bf + idx0) = o;
        } else {
            // noisy-net effective weights
            for (int n = tid; n < H1; n += 128) {
                float fia = fsgnsqrt(ei_a[n]);
                float fiv = fsgnsqrt(ei_v[n]);
                #pragma unroll
                for (int a = 0; a < ACT; a++)
                    wv[a * H1 + n] = adv_uw[a * H1 + n] + adv_sw[a * H1 + n] * fsgnsqrt(eo_a[a]) * fia;
                wv[5 * H1 + n] = v_uw[n] + v_sw[n] * fsgnsqrt(eo_v[0]) * fiv;
            }
            if (tid < ACT) bias[tid] = adv_ub[tid] + adv_sb[tid] * fsgnsqrt(eo_a[tid]);
            if (tid == ACT) bias[5] = v_ub[0] + v_sb[0] * fsgnsqrt(eo_v[0]);
        }
        return;
    }

    // ---- feat role ----
    __shared__ float xrow[XROW];
    __shared__ float sWg[NDC * NDC];
    __shared__ float sbg[NDC];
    __shared__ int   snd[NPOS];
    __shared__ int   sfirst[NPOS];
    __shared__ float scw[NPOS];           // cnt * dis (valid at first indices)
    __shared__ float sdis[NPOS];
    __shared__ int   sNB[NPOS][4];        // first idx of each grid-neighbor value (127=absent)
    __shared__ float sM[NPOS * NDCP];
    __shared__ int   gnnBase[48];         // sfirst[k*10+t]*NDCP     (t = 0..5)
    __shared__ int   gOut[48];            // k*98 + t*12
    __shared__ int   eachBase[48];        // k*PERK + (mf - k*10)*NDD
    __shared__ int   eOut[48];            // k*98 + 74 + t*4
    // tbl (u32[1024], live until scalar phase) and sH (f32[1040], live after) share storage:
    __shared__ __align__(16) char uShared[NPOS * NDCP * 4];
    unsigned int* tbl = (unsigned int*)uShared;
    float* sH = (float*)uShared;

    const float4* xp4 = (const float4*)(x + (size_t)bid * XROW);
    float4* xr4 = (float4*)xrow;
    #pragma unroll
    for (int i = tid; i < XROW / 4; i += 128) xr4[i] = xp4[i];
    for (int i = tid; i < NDC * NDC; i += 128) sWg[i] = Wg[i];
    if (tid < NDC) sbg[tid] = bg[tid];
    #pragma unroll
    for (int i = tid; i < 1024; i += 128) tbl[i] = 127u;
    __syncthreads();

    if (tid < NPOS) {
        int k = tid / 10, m = tid % 10;
        int nd = (int)xrow[k * PERK + 160 + m];
        snd[tid] = nd;
        atomicMin(&tbl[nd], (unsigned)tid);   // cnt bits are 0 in this phase -> pure min on first
    }
    __syncthreads();
    if (tid < NPOS) atomicAdd(&tbl[snd[tid]], 256u);   // cnt in bits 8+
    __syncthreads();

    // scalar phase: per-node values (80 threads) — also fills the 48 gather-base tables
    if (tid < NPOS) {
        const int i = tid;
        const int ndi = snd[i];
        const int k = i / 10;
        const int m = i - k * 10;
        const int kbase = k * 10;
        int r = ndi >> 5, c = ndi & 31;
        int nb0 = (((r + 31) & 31) << 5) | c;
        int nb1 = (((r + 1) & 31) << 5) | c;
        int nb2 = (r << 5) | ((c + 31) & 31);
        int nb3 = (r << 5) | ((c + 1) & 31);
        unsigned v = tbl[ndi];
        int f = (int)(v & 0xFFu);
        int cnt = (int)(v >> 8);
        unsigned v0 = tbl[nb0], v1 = tbl[nb1], v2 = tbl[nb2], v3 = tbl[nb3];
        sNB[i][0] = (int)(v0 & 0xFFu);
        sNB[i][1] = (int)(v1 & 0xFFu);
        sNB[i][2] = (int)(v2 & 0xFFu);
        sNB[i][3] = (int)(v3 & 0xFFu);
        int adjd = (int)((v0 >> 8) + (v1 >> 8) + (v2 >> 8) + (v3 >> 8));
        sfirst[i] = f;
        float dis = rsqrtf(1.0f + ((f == i) ? (float)adjd : 0.0f));
        sdis[i] = dis;
        scw[i] = (float)cnt * dis;
        if (m < 6) {
            int mf = 127;
            #pragma unroll
            for (int jj = 9; jj >= 0; jj--) {
                if (snd[kbase + jj] == ndi) mf = jj;   // within-group first (relative)
            }
            int pair = k * 6 + m;
            gnnBase[pair]  = f * NDCP;
            gOut[pair]     = k * 98 + m * 12;
            eachBase[pair] = k * PERK + mf * NDD;
            eOut[pair]     = k * 98 + 74 + m * 4;
        }
    }
    // M = all_info @ Wg: 240 quad-items (each computes 4 of the 12 outputs for one row)
    for (int p = tid; p < NPOS * 3; p += 128) {
        int i = p / 3, dq = (p - i * 3) * 4;
        int off = (i / 10) * PERK + (i % 10) * NDD + NDE;
        float s0 = 0.f, s1 = 0.f, s2 = 0.f, s3 = 0.f;
        #pragma unroll
        for (int c2 = 0; c2 < NDC; c2++) {
            float xv = xrow[off + c2];
            s0 += xv * sWg[c2 * NDC + dq];
            s1 += xv * sWg[c2 * NDC + dq + 1];
            s2 += xv * sWg[c2 * NDC + dq + 2];
            s3 += xv * sWg[c2 * NDC + dq + 3];
        }
        float* mp = sM + i * NDCP + dq;
        mp[0] = s0; mp[1] = s1; mp[2] = s2; mp[3] = s3;
    }
    __syncthreads();   // tbl dead beyond this point; sH may now be written

    // H only at FIRST rows (gather reads sH[sfirst[...]] which is always a first index)
    for (int p = tid; p < NPOS * NDC; p += 128) {
        int t = p / NDC, d = p - t * NDC;
        if (sfirst[t] == t) {
            float dt = sdis[t];
            float a = dt * dt * sM[t * NDCP + d];
            #pragma unroll
            for (int X = 0; X < 4; X++) {
                int sX = sNB[t][X];
                if (sX < NPOS) a += scw[sX] * dt * sM[sX * NDCP + d];
            }
            sH[t * NDCP + d] = fmaxf(a + sbg[d], 0.f);
        }
    }
    __syncthreads();

    // structured gather: gnn 576 | each 192 | els 16 | pad 16
    unsigned short* fout = featbf + (size_t)bid * FEATP;
    for (int p = tid; p < 576; p += 128) {
        int pair = p / 12, d = p - pair * 12;
        fout[gOut[pair] + d] = f2bf(sH[gnnBase[pair] + d]);
    }
    for (int p = tid; p < 192; p += 128) {
        int pair = p >> 2, e = p & 3;
        fout[eOut[pair] + e] = f2bf(xrow[eachBase[pair] + e]);
    }
    if (tid < 32) {
        if (tid < 16) {
            int k = tid >> 1, j = tid & 1;
            fout[k * 98 + 72 + j] = f2bf(xrow[k * PERK + 170 + j]);
        } else {
            fout[FEAT + tid - 16] = 0;
        }
    }
}

// ---------------- K2: h = relu(feat @ W1^T + b1), bf16 MFMA, 64x32 tile ----------------
#define LDF(p, kk) __builtin_bit_cast(bf16x8, *(const uint4*)((p) + (kk) * 32))

__global__ __launch_bounds__(256) void k_gemm(const unsigned short* __restrict__ A,
                                              const unsigned short* __restrict__ Bw,
                                              const float* __restrict__ b1,
                                              float* __restrict__ h, int nB)
{
    int tid = threadIdx.x;
    int lane = tid & 63;
    int w = tid >> 6;
    int wg = ((int)blockIdx.x & 7) * 128 + ((int)blockIdx.x >> 3);   // bm-chunked XCD swizzle
    int bm = (wg >> 4) * 64;
    int bn = (wg & 15) * 32;
    int wr = w >> 1, wc = w & 1;
    int l15 = lane & 15;
    int kb = (lane >> 4) * 8;

    const unsigned short* pa0 = A + (size_t)(bm + wr * 32 + l15) * FEATP + kb;
    const unsigned short* pa1 = pa0 + 16 * FEATP;
    const unsigned short* pb0 = Bw + (size_t)(bn + wc * 16 + l15) * FEATP + kb;

    f32x4 c0 = {0, 0, 0, 0}, c1 = {0, 0, 0, 0};
    bf16x8 a0  = LDF(pa0, 0);
    bf16x8 a1  = LDF(pa1, 0);
    bf16x8 bb0 = LDF(pb0, 0);
    #pragma unroll
    for (int kk = 0; kk < KSTEPS - 1; kk++) {
        bf16x8 na0  = LDF(pa0, kk + 1);
        bf16x8 na1  = LDF(pa1, kk + 1);
        bf16x8 nbb0 = LDF(pb0, kk + 1);
        c0 = __builtin_amdgcn_mfma_f32_16x16x32_bf16(a0, bb0, c0, 0, 0, 0);
        c1 = __builtin_amdgcn_mfma_f32_16x16x32_bf16(a1, bb0, c1, 0, 0, 0);
        a0 = na0; a1 = na1; bb0 = nbb0;
    }
    c0 = __builtin_amdgcn_mfma_f32_16x16x32_bf16(a0, bb0, c0, 0, 0, 0);
    c1 = __builtin_amdgcn_mfma_f32_16x16x32_bf16(a1, bb0, c1, 0, 0, 0);

    // C/D: col = lane&15, row = (lane>>4)*4 + reg  [m89]
    int row0 = bm + wr * 32 + (lane >> 4) * 4;
    int col0 = bn + wc * 16 + l15;
    float bias0 = b1[col0];
    #pragma unroll
    for (int r = 0; r < 4; r++) {
        h[(size_t)(row0 + r) * H1 + col0]      = fmaxf(c0[r] + bias0, 0.f);
        h[(size_t)(row0 + 16 + r) * H1 + col0] = fmaxf(c1[r] + bias0, 0.f);
    }
}

// ---------------- K3: dueling head, one wave per batch row ----------------
__global__ __launch_bounds__(256) void k_out(const float* __restrict__ h,
                                             const float* __restrict__ wv,
                                             const float* __restrict__ bias,
                                             float* __restrict__ out, int nB)
{
    int wave = blockIdx.x * 4 + (threadIdx.x >> 6);
    int lane = threadIdx.x & 63;
    if (wave >= nB) return;
    const float4* hb4 = (const float4*)(h + (size_t)wave * H1 + lane * 8);
    float4 h0 = hb4[0], h1 = hb4[1];
    float acc[6];
    #pragma unroll
    for (int a = 0; a < 6; a++) {
        const float4* wp4 = (const float4*)(wv + a * H1 + lane * 8);
        float4 w0 = wp4[0], w1 = wp4[1];
        acc[a] = h0.x * w0.x + h0.y * w0.y + h0.z * w0.z + h0.w * w0.w
               + h1.x * w1.x + h1.y * w1.y + h1.z * w1.z + h1.w * w1.w;
    }
    #pragma unroll
    for (int a = 0; a < 6; a++) {
        #pragma unroll
        for (int off = 32; off > 0; off >>= 1) acc[a] += __shfl_xor(acc[a], off, 64);
    }
    float adv[5], ssum = 0.f;
    #pragma unroll
    for (int a = 0; a < 5; a++) { adv[a] = acc[a] + bias[a]; ssum += adv[a]; }
    float vv = acc[5] + bias[5];
    if (lane < 5) out[(size_t)wave * 5 + lane] = vv + adv[lane] - ssum * 0.2f;
}

extern "C" void kernel_launch(void* const* d_in, const int* in_sizes, int n_in,
                              void* d_out, int out_size, void* d_ws, size_t ws_size,
                              hipStream_t stream)
{
    const float* x      = (const float*)d_in[0];
    const float* Wg     = (const float*)d_in[1];
    const float* bg     = (const float*)d_in[2];
    const float* W1     = (const float*)d_in[3];
    const float* b1     = (const float*)d_in[4];
    const float* adv_uw = (const float*)d_in[5];
    const float* adv_sw = (const float*)d_in[6];
    const float* adv_ub = (const float*)d_in[7];
    const float* adv_sb = (const float*)d_in[8];
    const float* v_uw   = (const float*)d_in[9];
    const float* v_sw   = (const float*)d_in[10];
    const float* v_ub   = (const float*)d_in[11];
    const float* v_sb   = (const float*)d_in[12];
    const float* ei_a   = (const float*)d_in[13];
    const float* eo_a   = (const float*)d_in[14];
    const float* ei_v   = (const float*)d_in[15];
    const float* eo_v   = (const float*)d_in[16];

    int nB = in_sizes[0] / XROW;   // 4096

    char* ws = (char*)d_ws;
    size_t off_feat = (size_t)H1 * FEATP * 2;                       // 819200
    unsigned short* w1bf   = (unsigned short*)ws;
    unsigned short* featbf = (unsigned short*)(ws + off_feat);
    float* h    = (float*)(ws + off_feat + (size_t)nB * FEATP * 2);
    float* wv   = (float*)((char*)h + (size_t)nB * H1 * 4);
    float* biasv = wv + 6 * H1;
    float* out  = (float*)d_out;

    // fused: nB feat blocks + 800 W1-convert blocks + 1 noisy block
    hipLaunchKernelGGL(k_pre, dim3(nB + 801), dim3(128), 0, stream,
                       x, Wg, bg, featbf, W1, w1bf,
                       adv_uw, adv_sw, adv_ub, adv_sb, v_uw, v_sw, v_ub, v_sb,
                       ei_a, eo_a, ei_v, eo_v, wv, biasv, nB);
    hipLaunchKernelGGL(k_gemm, dim3((nB / 64) * (H1 / 32)), dim3(256), 0, stream,
                       featbf, w1bf, b1, h, nB);
    hipLaunchKernelGGL(k_out, dim3((nB + 3) / 4), dim3(256), 0, stream, h, wv, biasv, out, nB);
}